// Round 1
// baseline (265.751 us; speedup 1.0000x reference)
//
#include <hip/hip_runtime.h>

// StandGCN2: 2-layer GCN, N=100000, E=600000, 128->128(relu)->64, bf16 I/O.
// R10: attack fill_k scatter-write amplification (41 MB WRITE for 4.8 MB payload,
// 1 TB/s effective). (a) XCD-ownership-partitioned fill: group g=blockIdx%8 owns
// dst range [g*N/8,(g+1)*N/8) -> sp write window ~600KB, L2-resident; edge list
// read once per XCD (streaming). (b) Fuse fill with gemm1 (independent stages)
// by block role: blocks 0..255 fill, 256..767 gemm. (c) Fold count into prep
// dispatch; cnt zeroed via hipMemsetAsync.
// Pipeline (6 dispatches + memset): memset(cnt) -> prepcount -> scan1 -> scan23
// -> fillgemm(x@W1 -> h MFMA || CSR fill) -> fusedB -> agg2.

typedef unsigned short u16;
typedef unsigned int u32;
typedef __attribute__((ext_vector_type(8))) short bf16x8;
typedef __attribute__((ext_vector_type(4))) float f32x4;

__device__ __forceinline__ float b2f(u16 s) {
  return __uint_as_float(((u32)s) << 16);
}
__device__ __forceinline__ u16 f2b(float f) {
  u32 u = __float_as_uint(f);
  u32 r = (u + 0x7FFFu + ((u >> 16) & 1u)) >> 16;
  return (u16)r;
}
__device__ __forceinline__ u32 pk2(float a, float b) {
  return (u32)f2b(a) | ((u32)f2b(b) << 16);
}
__device__ __forceinline__ void dec8(uint4 v, float f[8]) {
  f[0] = __uint_as_float(v.x << 16);
  f[1] = __uint_as_float(v.x & 0xFFFF0000u);
  f[2] = __uint_as_float(v.y << 16);
  f[3] = __uint_as_float(v.y & 0xFFFF0000u);
  f[4] = __uint_as_float(v.z << 16);
  f[5] = __uint_as_float(v.z & 0xFFFF0000u);
  f[6] = __uint_as_float(v.w << 16);
  f[7] = __uint_as_float(v.w & 0xFFFF0000u);
}
__device__ __forceinline__ void fma8(uint4 v, float d, float acc[8]) {
  acc[0] = fmaf(__uint_as_float(v.x << 16), d, acc[0]);
  acc[1] = fmaf(__uint_as_float(v.x & 0xFFFF0000u), d, acc[1]);
  acc[2] = fmaf(__uint_as_float(v.y << 16), d, acc[2]);
  acc[3] = fmaf(__uint_as_float(v.y & 0xFFFF0000u), d, acc[3]);
  acc[4] = fmaf(__uint_as_float(v.z << 16), d, acc[4]);
  acc[5] = fmaf(__uint_as_float(v.z & 0xFFFF0000u), d, acc[5]);
  acc[6] = fmaf(__uint_as_float(v.w << 16), d, acc[6]);
  acc[7] = fmaf(__uint_as_float(v.w & 0xFFFF0000u), d, acc[7]);
}

// ---- prepcount: [0,NB) prep (probe + weight convert); [NB,NB+eb) count ----
// cnt is pre-zeroed by hipMemsetAsync.

__global__ __launch_bounds__(256) void prepcount_k(const void* __restrict__ W1,
                                                   const void* __restrict__ b1,
                                                   const void* __restrict__ W2,
                                                   const void* __restrict__ b2,
                                                   u16* __restrict__ W1b, u16* __restrict__ ob1,
                                                   u16* __restrict__ W2t, u16* __restrict__ ob2,
                                                   int* __restrict__ mode,
                                                   const int* __restrict__ dst,
                                                   int* __restrict__ cnt, int E, int NB) {
  __shared__ int cnt_s;
  const int tid = threadIdx.x;

  if ((int)blockIdx.x >= NB) {
    // count role
    int e = ((int)blockIdx.x - NB) * 256 + tid;
    if (e < E) atomicAdd(&cnt[dst[e]], 1);
    return;
  }

  // prep role: block-local dtype probe + weight convert
  if (tid == 0) cnt_s = 0;
  __syncthreads();
  int c = 0;
  for (int j = tid; j < 4096; j += 256) {
    u32 e = (((const u16*)W1)[j] >> 7) & 0xFFu;
    if (e >= 100u && e <= 130u) c++;
  }
  atomicAdd(&cnt_s, c);
  __syncthreads();
  const int m = (cnt_s < 3328) ? 1 : 0;  // 1 = fp32
  if (blockIdx.x == 0 && tid == 0) *mode = m;

  int i = blockIdx.x * 256 + tid;
  if (i < 24768) {
    int j = i;
    const void* src;
    u16* dstp;
    int sidx, didx;
    if (j < 16384) {
      src = W1; dstp = W1b; sidx = j; didx = j;  // plain copy
    } else if ((j -= 16384) < 128) {
      src = b1; dstp = ob1; sidx = j; didx = j;
    } else if ((j -= 128) < 8192) {
      int nn = j >> 7, k = j & 127;               // W2t[n][k] = W2[k][n]
      src = W2; dstp = W2t; sidx = k * 64 + nn; didx = j;
    } else {
      j -= 8192;
      src = b2; dstp = ob2; sidx = j; didx = j;
    }
    dstp[didx] = m ? f2b(((const float*)src)[sidx]) : ((const u16*)src)[sidx];
  }
}

// ---------------- scans (unchanged) ----------------

__global__ __launch_bounds__(256) void scan1(const int* __restrict__ cnt,
                                             int* __restrict__ offs,
                                             int* __restrict__ bsum, int np) {
  __shared__ int lds[256];
  int t = threadIdx.x;
  int i = blockIdx.x * 256 + t;
  int v = cnt[i];
  lds[t] = v;
  __syncthreads();
#pragma unroll
  for (int off = 1; off < 256; off <<= 1) {
    int add = (t >= off) ? lds[t - off] : 0;
    __syncthreads();
    lds[t] += add;
    __syncthreads();
  }
  offs[i] = lds[t] - v;
  if (t == 0) bsum[blockIdx.x] = lds[255];
}

__global__ __launch_bounds__(256) void scan23(const int* __restrict__ offs,
                                              const int* __restrict__ bsum,
                                              int* __restrict__ cursor,
                                              const int* __restrict__ cnt,
                                              float* __restrict__ dinv,
                                              int4* __restrict__ ninfo, int np) {
  __shared__ int lds[256];
  const int t = threadIdx.x, b = blockIdx.x;
  int part = 0;
  for (int k = t; k < b; k += 256) part += bsum[k];
  lds[t] = part;
  __syncthreads();
#pragma unroll
  for (int off = 128; off > 0; off >>= 1) {
    if (t < off) lds[t] += lds[t + off];
    __syncthreads();
  }
  const int pre = lds[0];
  int i = b * 256 + t;
  int o = offs[i] + pre;
  cursor[i] = o;
  int c = cnt[i];
  float dv = rsqrtf((float)c + 1.0f);  // +1 self-loop
  dinv[i] = dv;
  ninfo[i] = make_int4(o, c, __float_as_int(dv), 0);
}

// ---- fillgemm: blocks [0,256) = XCD-partitioned CSR fill; [256,768) = gemm1 ----
// Fill: group g = blockIdx&7 (round-robin XCD mapping) owns dst in
// [g*NPG,(g+1)*NPG) -> sp writes land in a contiguous ~600KB window that stays
// in that XCD's L2. The 32 blocks of a group partition [0,E) into chunks; each
// edge is read by one block per group (edge arrays fetched once per XCD,
// streaming) and written exactly once (by its owner group).
// Gemm (R2-proven layout): A[m=lane&15][k=(lane>>4)*8+j]; C/D col=lane&15,
// row=(lane>>4)*4+reg.

#define FILLB 256
#define GEMMB 512

__global__ __launch_bounds__(256) void fillgemm_k(const int* __restrict__ srcA,
                                                  const int* __restrict__ dstA,
                                                  int* __restrict__ cursor,
                                                  const float* __restrict__ dinv,
                                                  int2* __restrict__ sp, int E, int n,
                                                  const void* __restrict__ Araw,
                                                  const u16* __restrict__ W,
                                                  u16* __restrict__ out, int M,
                                                  const int* __restrict__ mode) {
  __shared__ __align__(16) u16 Wt[128 * 136];
  __shared__ __align__(16) u16 As[64 * 136];
  const int tid = threadIdx.x;

  if ((int)blockIdx.x < FILLB) {
    const int g = blockIdx.x & 7;      // XCD group (round-robin assumption)
    const int j = blockIdx.x >> 3;     // chunk index within group, 0..31
    const int NPG = (n + 7) >> 3;
    const int lo = g * NPG;
    const int hi = min(n, lo + NPG);
    const int chunk = (E + 31) >> 5;
    const int e1 = min(E, (j + 1) * chunk);
    for (int e = j * chunk + tid; e < e1; e += 256) {
      int d = dstA[e];
      int s = srcA[e];
      if (d >= lo && d < hi) {
        float ds = dinv[s];
        int p = atomicAdd(&cursor[d], 1);
        sp[p] = make_int2(s, __float_as_int(ds));
      }
    }
    return;
  }

  // ---- gemm role: h = x @ W1 ----
  const int mcv = *mode;

  for (int idx = tid; idx < 128 * 128; idx += 256) {
    int nn = idx & 127;
    int k = idx >> 7;
    Wt[nn * 136 + k] = W[k * 128 + nn];
  }
  __syncthreads();

  const int wv = tid >> 6, lane = tid & 63, lr = lane & 15, lq = lane >> 4;
  const int ntiles = (M + 63) >> 6;

  for (int t = (int)blockIdx.x - FILLB; t < ntiles; t += GEMMB) {
    const int r0 = t * 64;
    __syncthreads();
    for (int idx = tid; idx < 64 * 16; idx += 256) {
      int row = idx >> 4, c = idx & 15;
      uint4 v = make_uint4(0u, 0u, 0u, 0u);
      if (r0 + row < M) {
        if (mcv) {
          const float* xf = (const float*)Araw + (size_t)(r0 + row) * 128 + c * 8;
          float4 f0 = *(const float4*)xf;
          float4 f1 = *(const float4*)(xf + 4);
          v.x = pk2(f0.x, f0.y);
          v.y = pk2(f0.z, f0.w);
          v.z = pk2(f1.x, f1.y);
          v.w = pk2(f1.z, f1.w);
        } else {
          v = *(const uint4*)((const u16*)Araw + (size_t)(r0 + row) * 128 + c * 8);
        }
      }
      *(uint4*)&As[row * 136 + c * 8] = v;
    }
    __syncthreads();

    bf16x8 a[4];
#pragma unroll
    for (int s = 0; s < 4; ++s)
      a[s] = *(const bf16x8*)&As[(wv * 16 + lr) * 136 + s * 32 + lq * 8];

#pragma unroll
    for (int nt = 0; nt < 8; ++nt) {
      f32x4 acc = {0.f, 0.f, 0.f, 0.f};
#pragma unroll
      for (int s = 0; s < 4; ++s) {
        bf16x8 b = *(const bf16x8*)&Wt[(nt * 16 + lr) * 136 + s * 32 + lq * 8];
        acc = __builtin_amdgcn_mfma_f32_16x16x32_bf16(a[s], b, acc, 0, 0, 0);
      }
#pragma unroll
      for (int r = 0; r < 4; ++r) {
        int row = r0 + wv * 16 + lq * 4 + r;
        if (row < M) out[(size_t)row * 128 + nt * 16 + lr] = f2b(acc[r]);
      }
    }
  }
}

// ---- fusedB: gather-aggregate h (16 nodes/block, quarter-wave, unroll-4)
//      -> +b1, relu -> LDS tile -> MFMA W2t -> g[N,64] ----

__global__ __launch_bounds__(256) void fusedB_k(const u16* __restrict__ h,
                                                const int2* __restrict__ sp,
                                                const int4* __restrict__ ninfo,
                                                const u16* __restrict__ b1,
                                                const u16* __restrict__ W2t,
                                                u16* __restrict__ g, int n) {
  __shared__ __align__(16) u16 As[16 * 136];
  const int tid = threadIdx.x, wv = tid >> 6, lane = tid & 63;
  const int lq = lane >> 4, lr = lane & 15;
  const int base = blockIdx.x * 16;
  const int i = base + wv * 4 + lq;
  const bool valid = (i < n);

  int start = 0, c = 0;
  float di = 0.f;
  if (valid) {
    int4 ni = ninfo[i];
    start = ni.x;
    c = ni.y;
    di = __int_as_float(ni.z);
  }
  float acc[8];
  {
    uint4 v = valid ? *(const uint4*)(h + (size_t)i * 128 + lr * 8)
                    : make_uint4(0u, 0u, 0u, 0u);
    float f[8];
    dec8(v, f);
#pragma unroll
    for (int j = 0; j < 8; ++j) acc[j] = f[j] * di;
  }
  const int bl = lq * 16;
  for (int bs = 0; __any(bs < c); bs += 16) {
    int m = c - bs;
    m = m < 0 ? 0 : (m > 16 ? 16 : m);
    int s = 0, db = 0;
    if (lr < m) {
      int2 p = sp[start + bs + lr];
      s = p.x;
      db = p.y;
    }
    int mmw = m;
    mmw = max(mmw, __shfl_xor(mmw, 16));
    mmw = max(mmw, __shfl_xor(mmw, 32));
    for (int e = 0; e < mmw; e += 4) {
      int s0 = __shfl(s, bl + e), s1 = __shfl(s, bl + e + 1);
      int s2 = __shfl(s, bl + e + 2), s3 = __shfl(s, bl + e + 3);
      float d0 = __int_as_float(__shfl(db, bl + e));
      float d1 = __int_as_float(__shfl(db, bl + e + 1));
      float d2 = __int_as_float(__shfl(db, bl + e + 2));
      float d3 = __int_as_float(__shfl(db, bl + e + 3));
      uint4 v0 = *(const uint4*)(h + (size_t)s0 * 128 + lr * 8);
      uint4 v1 = *(const uint4*)(h + (size_t)s1 * 128 + lr * 8);
      uint4 v2 = *(const uint4*)(h + (size_t)s2 * 128 + lr * 8);
      uint4 v3 = *(const uint4*)(h + (size_t)s3 * 128 + lr * 8);
      fma8(v0, d0, acc);
      fma8(v1, d1, acc);
      fma8(v2, d2, acc);
      fma8(v3, d3, acc);
    }
  }
  // h1 = relu(acc*di + b1) -> As tile (bf16)
  {
    uint4 bv = *(const uint4*)(b1 + lr * 8);
    float bf[8];
    dec8(bv, bf);
    float o[8];
#pragma unroll
    for (int j = 0; j < 8; ++j) o[j] = fmaxf(fmaf(acc[j], di, bf[j]), 0.f);
    uint4 ov;
    ov.x = pk2(o[0], o[1]);
    ov.y = pk2(o[2], o[3]);
    ov.z = pk2(o[4], o[5]);
    ov.w = pk2(o[6], o[7]);
    *(uint4*)&As[(wv * 4 + lq) * 136 + lr * 8] = ov;
  }
  __syncthreads();

  // W2 MFMA: wave wv -> col tile wv (cols 16wv..16wv+15)
  bf16x8 a[4];
#pragma unroll
  for (int s = 0; s < 4; ++s)
    a[s] = *(const bf16x8*)&As[lr * 136 + s * 32 + lq * 8];
  {
    const int nt = wv;
    f32x4 acc4 = {0.f, 0.f, 0.f, 0.f};
#pragma unroll
    for (int s = 0; s < 4; ++s) {
      bf16x8 b = *(const bf16x8*)&W2t[(nt * 16 + lr) * 128 + s * 32 + lq * 8];
      acc4 = __builtin_amdgcn_mfma_f32_16x16x32_bf16(a[s], b, acc4, 0, 0, 0);
    }
#pragma unroll
    for (int r = 0; r < 4; ++r) {
      int row = base + lq * 4 + r;
      if (row < n) g[(size_t)row * 64 + nt * 16 + lr] = f2b(acc4[r]);
    }
  }
}

// ---- agg2: oct-wave over g, 8 nodes/wave, unroll-4 ----

__global__ __launch_bounds__(256) void agg2_k(const u16* __restrict__ g,
                                              const int2* __restrict__ sp,
                                              const int4* __restrict__ ninfo,
                                              const u16* __restrict__ b2,
                                              void* __restrict__ outv, int n,
                                              const int* __restrict__ mode) {
  const int lane = threadIdx.x & 63;
  const int o8 = lane >> 3, l8 = lane & 7;
  const int i = blockIdx.x * 32 + (threadIdx.x >> 6) * 8 + o8;
  const bool valid = (i < n);

  int start = 0, c = 0;
  float di = 0.f;
  if (valid) {
    int4 ni = ninfo[i];
    start = ni.x;
    c = ni.y;
    di = __int_as_float(ni.z);
  }
  float acc[8];
  {
    uint4 v = valid ? *(const uint4*)(g + (size_t)i * 64 + l8 * 8)
                    : make_uint4(0u, 0u, 0u, 0u);
    float f[8];
    dec8(v, f);
#pragma unroll
    for (int j = 0; j < 8; ++j) acc[j] = f[j] * di;
  }
  const int bl = o8 * 8;
  for (int base = 0; __any(base < c); base += 8) {
    int m = c - base;
    m = m < 0 ? 0 : (m > 8 ? 8 : m);
    int s = 0, db = 0;
    if (l8 < m) {
      int2 p = sp[start + base + l8];
      s = p.x;
      db = p.y;
    }
    int mmw = m;
    mmw = max(mmw, __shfl_xor(mmw, 8));
    mmw = max(mmw, __shfl_xor(mmw, 16));
    mmw = max(mmw, __shfl_xor(mmw, 32));
    for (int e = 0; e < mmw; e += 4) {
      int s0 = __shfl(s, bl + e), s1 = __shfl(s, bl + e + 1);
      int s2 = __shfl(s, bl + e + 2), s3 = __shfl(s, bl + e + 3);
      float d0 = __int_as_float(__shfl(db, bl + e));
      float d1 = __int_as_float(__shfl(db, bl + e + 1));
      float d2 = __int_as_float(__shfl(db, bl + e + 2));
      float d3 = __int_as_float(__shfl(db, bl + e + 3));
      uint4 v0 = *(const uint4*)(g + (size_t)s0 * 64 + l8 * 8);
      uint4 v1 = *(const uint4*)(g + (size_t)s1 * 64 + l8 * 8);
      uint4 v2 = *(const uint4*)(g + (size_t)s2 * 64 + l8 * 8);
      uint4 v3 = *(const uint4*)(g + (size_t)s3 * 64 + l8 * 8);
      fma8(v0, d0, acc);
      fma8(v1, d1, acc);
      fma8(v2, d2, acc);
      fma8(v3, d3, acc);
    }
  }
  if (valid) {
    uint4 bv = *(const uint4*)(b2 + l8 * 8);
    float bf[8];
    dec8(bv, bf);
    float o[8];
#pragma unroll
    for (int j = 0; j < 8; ++j) o[j] = fmaf(acc[j], di, bf[j]);
    if (*mode) {
      float* op = (float*)outv + (size_t)i * 64 + l8 * 8;
      *(float4*)op = make_float4(o[0], o[1], o[2], o[3]);
      *(float4*)(op + 4) = make_float4(o[4], o[5], o[6], o[7]);
    } else {
      uint4 ov;
      ov.x = pk2(o[0], o[1]);
      ov.y = pk2(o[2], o[3]);
      ov.z = pk2(o[4], o[5]);
      ov.w = pk2(o[6], o[7]);
      *(uint4*)((u16*)outv + (size_t)i * 64 + l8 * 8) = ov;
    }
  }
}

// ================= launch =================

extern "C" void kernel_launch(void* const* d_in, const int* in_sizes, int n_in,
                              void* d_out, int out_size, void* d_ws, size_t ws_size,
                              hipStream_t stream) {
  const void* x_raw  = d_in[0];
  const int*  ei     = (const int*)d_in[1];
  const void* W1_raw = d_in[2];
  const void* b1_raw = d_in[3];
  const void* W2_raw = d_in[4];
  const void* b2_raw = d_in[5];

  const int N = in_sizes[0] / 128;
  const int E = in_sizes[1] / 2;
  const int NP = ((N + 255) / 256) * 256;
  const int NB = NP / 256;

  char* ws = (char*)d_ws;
  size_t off = 0;
  auto alloc = [&](size_t bytes) -> void* {
    void* p = ws + off;
    off = (off + bytes + 255) & ~(size_t)255;
    return p;
  };
  int*   mode   = (int*)alloc(4);
  int*   cnt    = (int*)alloc((size_t)NP * 4);
  float* dinv   = (float*)alloc((size_t)NP * 4);
  int*   offs   = (int*)alloc((size_t)NP * 4);
  int*   cursor = (int*)alloc((size_t)NP * 4);
  int*   bsum   = (int*)alloc(1024 * 4);
  int4*  ninfo  = (int4*)alloc((size_t)NP * 16);
  int2*  sp     = (int2*)alloc((size_t)E * 8);
  u16*   W1b    = (u16*)alloc((size_t)128 * 128 * 2);
  u16*   b1b    = (u16*)alloc(128 * 2);
  u16*   W2t    = (u16*)alloc((size_t)64 * 128 * 2);
  u16*   b2b    = (u16*)alloc(64 * 2);
  u16*   h      = (u16*)alloc((size_t)N * 128 * 2);
  u16*   g      = (u16*)alloc((size_t)N * 64 * 2);

  const int eb = (E + 255) / 256;

  hipMemsetAsync(cnt, 0, (size_t)NP * 4, stream);
  prepcount_k<<<NB + eb, 256, 0, stream>>>(W1_raw, b1_raw, W2_raw, b2_raw,
                                           W1b, b1b, W2t, b2b, mode,
                                           ei + E, cnt, E, NB);
  scan1<<<NB, 256, 0, stream>>>(cnt, offs, bsum, NP);
  scan23<<<NB, 256, 0, stream>>>(offs, bsum, cursor, cnt, dinv, ninfo, NP);
  fillgemm_k<<<FILLB + GEMMB, 256, 0, stream>>>(ei, ei + E, cursor, dinv, sp, E, N,
                                                x_raw, W1b, h, N, mode);
  fusedB_k<<<(N + 15) / 16, 256, 0, stream>>>(h, sp, ninfo, b1b, W2t, g, N);
  agg2_k<<<(N + 31) / 32, 256, 0, stream>>>(g, sp, ninfo, b2b, d_out, N, mode);
}

// Round 2
// 234.780 us; speedup vs baseline: 1.1319x; 1.1319x over previous
//
#include <hip/hip_runtime.h>

// StandGCN2: 2-layer GCN, N=100000, E=600000, 128->128(relu)->64, bf16 I/O.
// R11: R10's fill+gemm fusion REVERTED (92us fused vs 45+20 separate: 52KB LDS
// capped occupancy at 16%, and fill's streaming edge reads evicted the sp
// window from L2 -> WRITE still 28MB). New fill = 2-phase radix partition:
//   part_k: LDS-staged segment histogram + bulk reserve -> tmp writes are
//           contiguous ~400B runs per (block,bucket): no line amplification.
//   scatter_k: per-bucket scatter tmp->sp; bucket sp window ~98KB, all blocks
//           of a bucket pinned to ONE XCD (blockIdx===bucket mod 8) so each sp
//           line is dirtied in exactly one L2 and written back once.
// Pipeline: memset(cnt) -> prepcount -> scan1 -> scan23(+bucket bases) ->
// part -> scatter -> gemm1 -> fusedB -> agg2.

typedef unsigned short u16;
typedef unsigned int u32;
typedef __attribute__((ext_vector_type(8))) short bf16x8;
typedef __attribute__((ext_vector_type(4))) float f32x4;

#define BSH 11                 // bucket shift: 2048 nodes/bucket
#define SEG 2560               // edges per part_k block (LDS-staged)

__device__ __forceinline__ float b2f(u16 s) {
  return __uint_as_float(((u32)s) << 16);
}
__device__ __forceinline__ u16 f2b(float f) {
  u32 u = __float_as_uint(f);
  u32 r = (u + 0x7FFFu + ((u >> 16) & 1u)) >> 16;
  return (u16)r;
}
__device__ __forceinline__ u32 pk2(float a, float b) {
  return (u32)f2b(a) | ((u32)f2b(b) << 16);
}
__device__ __forceinline__ void dec8(uint4 v, float f[8]) {
  f[0] = __uint_as_float(v.x << 16);
  f[1] = __uint_as_float(v.x & 0xFFFF0000u);
  f[2] = __uint_as_float(v.y << 16);
  f[3] = __uint_as_float(v.y & 0xFFFF0000u);
  f[4] = __uint_as_float(v.z << 16);
  f[5] = __uint_as_float(v.z & 0xFFFF0000u);
  f[6] = __uint_as_float(v.w << 16);
  f[7] = __uint_as_float(v.w & 0xFFFF0000u);
}
__device__ __forceinline__ void fma8(uint4 v, float d, float acc[8]) {
  acc[0] = fmaf(__uint_as_float(v.x << 16), d, acc[0]);
  acc[1] = fmaf(__uint_as_float(v.x & 0xFFFF0000u), d, acc[1]);
  acc[2] = fmaf(__uint_as_float(v.y << 16), d, acc[2]);
  acc[3] = fmaf(__uint_as_float(v.y & 0xFFFF0000u), d, acc[3]);
  acc[4] = fmaf(__uint_as_float(v.z << 16), d, acc[4]);
  acc[5] = fmaf(__uint_as_float(v.z & 0xFFFF0000u), d, acc[5]);
  acc[6] = fmaf(__uint_as_float(v.w << 16), d, acc[6]);
  acc[7] = fmaf(__uint_as_float(v.w & 0xFFFF0000u), d, acc[7]);
}

// ---- prepcount: [0,NB) prep (probe + weight convert); [NB,NB+eb) count ----

__global__ __launch_bounds__(256) void prepcount_k(const void* __restrict__ W1,
                                                   const void* __restrict__ b1,
                                                   const void* __restrict__ W2,
                                                   const void* __restrict__ b2,
                                                   u16* __restrict__ W1b, u16* __restrict__ ob1,
                                                   u16* __restrict__ W2t, u16* __restrict__ ob2,
                                                   int* __restrict__ mode,
                                                   const int* __restrict__ dst,
                                                   int* __restrict__ cnt, int E, int NB) {
  __shared__ int cnt_s;
  const int tid = threadIdx.x;

  if ((int)blockIdx.x >= NB) {
    int e = ((int)blockIdx.x - NB) * 256 + tid;
    if (e < E) atomicAdd(&cnt[dst[e]], 1);
    return;
  }

  if (tid == 0) cnt_s = 0;
  __syncthreads();
  int c = 0;
  for (int j = tid; j < 4096; j += 256) {
    u32 e = (((const u16*)W1)[j] >> 7) & 0xFFu;
    if (e >= 100u && e <= 130u) c++;
  }
  atomicAdd(&cnt_s, c);
  __syncthreads();
  const int m = (cnt_s < 3328) ? 1 : 0;  // 1 = fp32
  if (blockIdx.x == 0 && tid == 0) *mode = m;

  int i = blockIdx.x * 256 + tid;
  if (i < 24768) {
    int j = i;
    const void* src;
    u16* dstp;
    int sidx, didx;
    if (j < 16384) {
      src = W1; dstp = W1b; sidx = j; didx = j;
    } else if ((j -= 16384) < 128) {
      src = b1; dstp = ob1; sidx = j; didx = j;
    } else if ((j -= 128) < 8192) {
      int nn = j >> 7, k = j & 127;               // W2t[n][k] = W2[k][n]
      src = W2; dstp = W2t; sidx = k * 64 + nn; didx = j;
    } else {
      j -= 8192;
      src = b2; dstp = ob2; sidx = j; didx = j;
    }
    dstp[didx] = m ? f2b(((const float*)src)[sidx]) : ((const u16*)src)[sidx];
  }
}

// ---------------- scans ----------------

__global__ __launch_bounds__(256) void scan1(const int* __restrict__ cnt,
                                             int* __restrict__ offs,
                                             int* __restrict__ bsum, int np) {
  __shared__ int lds[256];
  int t = threadIdx.x;
  int i = blockIdx.x * 256 + t;
  int v = cnt[i];
  lds[t] = v;
  __syncthreads();
#pragma unroll
  for (int off = 1; off < 256; off <<= 1) {
    int add = (t >= off) ? lds[t - off] : 0;
    __syncthreads();
    lds[t] += add;
    __syncthreads();
  }
  offs[i] = lds[t] - v;
  if (t == 0) bsum[blockIdx.x] = lds[255];
}

__global__ __launch_bounds__(256) void scan23(const int* __restrict__ offs,
                                              const int* __restrict__ bsum,
                                              int* __restrict__ cursor,
                                              const int* __restrict__ cnt,
                                              float* __restrict__ dinv,
                                              int4* __restrict__ ninfo,
                                              int* __restrict__ bstart,
                                              int* __restrict__ bcursor, int np) {
  __shared__ int lds[256];
  const int t = threadIdx.x, b = blockIdx.x;
  int part = 0;
  for (int k = t; k < b; k += 256) part += bsum[k];
  lds[t] = part;
  __syncthreads();
#pragma unroll
  for (int off = 128; off > 0; off >>= 1) {
    if (t < off) lds[t] += lds[t + off];
    __syncthreads();
  }
  const int pre = lds[0];
  int i = b * 256 + t;
  int o = offs[i] + pre;
  cursor[i] = o;
  if ((i & ((1 << BSH) - 1)) == 0) {
    bstart[i >> BSH] = o;
    bcursor[i >> BSH] = o;
  }
  int c = cnt[i];
  float dv = rsqrtf((float)c + 1.0f);  // +1 self-loop
  dinv[i] = dv;
  ninfo[i] = make_int4(o, c, __float_as_int(dv), 0);
}

// ---- part_k: radix partition edges by dst bucket into tmp (sequential runs) ----

__global__ __launch_bounds__(256) void part_k(const int* __restrict__ src,
                                              const int* __restrict__ dst,
                                              int* __restrict__ bcursor,
                                              int2* __restrict__ tmp,
                                              int E, int NBK) {
  __shared__ int ls[SEG];
  __shared__ int ld_[SEG];
  __shared__ int hist[64];
  __shared__ int base_[64];
  const int tid = threadIdx.x;
  const int e0 = blockIdx.x * SEG;
  const int len = min(SEG, E - e0);

  if (tid < 64) hist[tid] = 0;
  __syncthreads();
  for (int j = tid; j < len; j += 256) {
    int s = src[e0 + j];
    int d = dst[e0 + j];
    ls[j] = s;
    ld_[j] = d;
    atomicAdd(&hist[d >> BSH], 1);
  }
  __syncthreads();
  if (tid < NBK) {
    int hh = hist[tid];
    base_[tid] = hh ? atomicAdd(&bcursor[tid], hh) : 0;
    hist[tid] = 0;  // reuse as rank counter
  }
  __syncthreads();
  for (int j = tid; j < len; j += 256) {
    int d = ld_[j];
    int bk = d >> BSH;
    int r = atomicAdd(&hist[bk], 1);
    tmp[base_[bk] + r] = make_int2(ls[j], d);
  }
}

// ---- scatter_k: per-bucket scatter tmp -> sp; bucket pinned to one XCD ----

__global__ __launch_bounds__(256) void scatter_k(const int2* __restrict__ tmp,
                                                 const int* __restrict__ bstart,
                                                 int* __restrict__ cursor,
                                                 const float* __restrict__ dinv,
                                                 int2* __restrict__ sp,
                                                 int E, int NBK) {
  const int x = blockIdx.x & 7;
  const int q = blockIdx.x >> 3;
  const int g = q >> 3, k = q & 7;   // K = 8 slices per bucket
  const int b = x + (g << 3);
  if (b >= NBK) return;
  const int bs = bstart[b];
  const int be = (b + 1 < NBK) ? bstart[b + 1] : E;
  const int len = be - bs;
  const int s0 = bs + (int)(((long long)len * k) >> 3);
  const int s1 = bs + (int)(((long long)len * (k + 1)) >> 3);
  for (int e = s0 + threadIdx.x; e < s1; e += 256) {
    int2 p = tmp[e];
    float ds = dinv[p.x];
    int pos = atomicAdd(&cursor[p.y], 1);
    sp[pos] = make_int2(p.x, __float_as_int(ds));
  }
}

// ---------------- gemm1: h = x @ W1 (dense MFMA, R2-proven) ----------------

__global__ __launch_bounds__(256) void gemm1_k(const void* __restrict__ Araw,
                                               const u16* __restrict__ W,
                                               u16* __restrict__ out, int M,
                                               const int* __restrict__ mode) {
  __shared__ __align__(16) u16 Wt[128 * 136];
  __shared__ __align__(16) u16 As[64 * 136];
  const int tid = threadIdx.x;
  const int mcv = *mode;

  for (int idx = tid; idx < 128 * 128; idx += 256) {
    int n = idx & 127;
    int k = idx >> 7;
    Wt[n * 136 + k] = W[k * 128 + n];
  }
  __syncthreads();

  const int wv = tid >> 6, lane = tid & 63, lr = lane & 15, lq = lane >> 4;
  const int ntiles = (M + 63) >> 6;

  for (int t = blockIdx.x; t < ntiles; t += gridDim.x) {
    const int r0 = t * 64;
    __syncthreads();
    for (int idx = tid; idx < 64 * 16; idx += 256) {
      int row = idx >> 4, c = idx & 15;
      uint4 v = make_uint4(0u, 0u, 0u, 0u);
      if (r0 + row < M) {
        if (mcv) {
          const float* xf = (const float*)Araw + (size_t)(r0 + row) * 128 + c * 8;
          float4 f0 = *(const float4*)xf;
          float4 f1 = *(const float4*)(xf + 4);
          v.x = pk2(f0.x, f0.y);
          v.y = pk2(f0.z, f0.w);
          v.z = pk2(f1.x, f1.y);
          v.w = pk2(f1.z, f1.w);
        } else {
          v = *(const uint4*)((const u16*)Araw + (size_t)(r0 + row) * 128 + c * 8);
        }
      }
      *(uint4*)&As[row * 136 + c * 8] = v;
    }
    __syncthreads();

    bf16x8 a[4];
#pragma unroll
    for (int s = 0; s < 4; ++s)
      a[s] = *(const bf16x8*)&As[(wv * 16 + lr) * 136 + s * 32 + lq * 8];

#pragma unroll
    for (int nt = 0; nt < 8; ++nt) {
      f32x4 acc = {0.f, 0.f, 0.f, 0.f};
#pragma unroll
      for (int s = 0; s < 4; ++s) {
        bf16x8 b = *(const bf16x8*)&Wt[(nt * 16 + lr) * 136 + s * 32 + lq * 8];
        acc = __builtin_amdgcn_mfma_f32_16x16x32_bf16(a[s], b, acc, 0, 0, 0);
      }
#pragma unroll
      for (int r = 0; r < 4; ++r) {
        int row = r0 + wv * 16 + lq * 4 + r;
        if (row < M) out[(size_t)row * 128 + nt * 16 + lr] = f2b(acc[r]);
      }
    }
  }
}

// ---- fusedB: gather-aggregate h -> +b1, relu -> MFMA W2t -> g[N,64] ----

__global__ __launch_bounds__(256) void fusedB_k(const u16* __restrict__ h,
                                                const int2* __restrict__ sp,
                                                const int4* __restrict__ ninfo,
                                                const u16* __restrict__ b1,
                                                const u16* __restrict__ W2t,
                                                u16* __restrict__ g, int n) {
  __shared__ __align__(16) u16 As[16 * 136];
  const int tid = threadIdx.x, wv = tid >> 6, lane = tid & 63;
  const int lq = lane >> 4, lr = lane & 15;
  const int base = blockIdx.x * 16;
  const int i = base + wv * 4 + lq;
  const bool valid = (i < n);

  int start = 0, c = 0;
  float di = 0.f;
  if (valid) {
    int4 ni = ninfo[i];
    start = ni.x;
    c = ni.y;
    di = __int_as_float(ni.z);
  }
  float acc[8];
  {
    uint4 v = valid ? *(const uint4*)(h + (size_t)i * 128 + lr * 8)
                    : make_uint4(0u, 0u, 0u, 0u);
    float f[8];
    dec8(v, f);
#pragma unroll
    for (int j = 0; j < 8; ++j) acc[j] = f[j] * di;
  }
  const int bl = lq * 16;
  for (int bs = 0; __any(bs < c); bs += 16) {
    int m = c - bs;
    m = m < 0 ? 0 : (m > 16 ? 16 : m);
    int s = 0, db = 0;
    if (lr < m) {
      int2 p = sp[start + bs + lr];
      s = p.x;
      db = p.y;
    }
    int mmw = m;
    mmw = max(mmw, __shfl_xor(mmw, 16));
    mmw = max(mmw, __shfl_xor(mmw, 32));
    for (int e = 0; e < mmw; e += 4) {
      int s0 = __shfl(s, bl + e), s1 = __shfl(s, bl + e + 1);
      int s2 = __shfl(s, bl + e + 2), s3 = __shfl(s, bl + e + 3);
      float d0 = __int_as_float(__shfl(db, bl + e));
      float d1 = __int_as_float(__shfl(db, bl + e + 1));
      float d2 = __int_as_float(__shfl(db, bl + e + 2));
      float d3 = __int_as_float(__shfl(db, bl + e + 3));
      uint4 v0 = *(const uint4*)(h + (size_t)s0 * 128 + lr * 8);
      uint4 v1 = *(const uint4*)(h + (size_t)s1 * 128 + lr * 8);
      uint4 v2 = *(const uint4*)(h + (size_t)s2 * 128 + lr * 8);
      uint4 v3 = *(const uint4*)(h + (size_t)s3 * 128 + lr * 8);
      fma8(v0, d0, acc);
      fma8(v1, d1, acc);
      fma8(v2, d2, acc);
      fma8(v3, d3, acc);
    }
  }
  {
    uint4 bv = *(const uint4*)(b1 + lr * 8);
    float bf[8];
    dec8(bv, bf);
    float o[8];
#pragma unroll
    for (int j = 0; j < 8; ++j) o[j] = fmaxf(fmaf(acc[j], di, bf[j]), 0.f);
    uint4 ov;
    ov.x = pk2(o[0], o[1]);
    ov.y = pk2(o[2], o[3]);
    ov.z = pk2(o[4], o[5]);
    ov.w = pk2(o[6], o[7]);
    *(uint4*)&As[(wv * 4 + lq) * 136 + lr * 8] = ov;
  }
  __syncthreads();

  bf16x8 a[4];
#pragma unroll
  for (int s = 0; s < 4; ++s)
    a[s] = *(const bf16x8*)&As[lr * 136 + s * 32 + lq * 8];
  {
    const int nt = wv;
    f32x4 acc4 = {0.f, 0.f, 0.f, 0.f};
#pragma unroll
    for (int s = 0; s < 4; ++s) {
      bf16x8 b = *(const bf16x8*)&W2t[(nt * 16 + lr) * 128 + s * 32 + lq * 8];
      acc4 = __builtin_amdgcn_mfma_f32_16x16x32_bf16(a[s], b, acc4, 0, 0, 0);
    }
#pragma unroll
    for (int r = 0; r < 4; ++r) {
      int row = base + lq * 4 + r;
      if (row < n) g[(size_t)row * 64 + nt * 16 + lr] = f2b(acc4[r]);
    }
  }
}

// ---- agg2: oct-wave over g, 8 nodes/wave, unroll-4 ----

__global__ __launch_bounds__(256) void agg2_k(const u16* __restrict__ g,
                                              const int2* __restrict__ sp,
                                              const int4* __restrict__ ninfo,
                                              const u16* __restrict__ b2,
                                              void* __restrict__ outv, int n,
                                              const int* __restrict__ mode) {
  const int lane = threadIdx.x & 63;
  const int o8 = lane >> 3, l8 = lane & 7;
  const int i = blockIdx.x * 32 + (threadIdx.x >> 6) * 8 + o8;
  const bool valid = (i < n);

  int start = 0, c = 0;
  float di = 0.f;
  if (valid) {
    int4 ni = ninfo[i];
    start = ni.x;
    c = ni.y;
    di = __int_as_float(ni.z);
  }
  float acc[8];
  {
    uint4 v = valid ? *(const uint4*)(g + (size_t)i * 64 + l8 * 8)
                    : make_uint4(0u, 0u, 0u, 0u);
    float f[8];
    dec8(v, f);
#pragma unroll
    for (int j = 0; j < 8; ++j) acc[j] = f[j] * di;
  }
  const int bl = o8 * 8;
  for (int base = 0; __any(base < c); base += 8) {
    int m = c - base;
    m = m < 0 ? 0 : (m > 8 ? 8 : m);
    int s = 0, db = 0;
    if (l8 < m) {
      int2 p = sp[start + base + l8];
      s = p.x;
      db = p.y;
    }
    int mmw = m;
    mmw = max(mmw, __shfl_xor(mmw, 8));
    mmw = max(mmw, __shfl_xor(mmw, 16));
    mmw = max(mmw, __shfl_xor(mmw, 32));
    for (int e = 0; e < mmw; e += 4) {
      int s0 = __shfl(s, bl + e), s1 = __shfl(s, bl + e + 1);
      int s2 = __shfl(s, bl + e + 2), s3 = __shfl(s, bl + e + 3);
      float d0 = __int_as_float(__shfl(db, bl + e));
      float d1 = __int_as_float(__shfl(db, bl + e + 1));
      float d2 = __int_as_float(__shfl(db, bl + e + 2));
      float d3 = __int_as_float(__shfl(db, bl + e + 3));
      uint4 v0 = *(const uint4*)(g + (size_t)s0 * 64 + l8 * 8);
      uint4 v1 = *(const uint4*)(g + (size_t)s1 * 64 + l8 * 8);
      uint4 v2 = *(const uint4*)(g + (size_t)s2 * 64 + l8 * 8);
      uint4 v3 = *(const uint4*)(g + (size_t)s3 * 64 + l8 * 8);
      fma8(v0, d0, acc);
      fma8(v1, d1, acc);
      fma8(v2, d2, acc);
      fma8(v3, d3, acc);
    }
  }
  if (valid) {
    uint4 bv = *(const uint4*)(b2 + l8 * 8);
    float bf[8];
    dec8(bv, bf);
    float o[8];
#pragma unroll
    for (int j = 0; j < 8; ++j) o[j] = fmaf(acc[j], di, bf[j]);
    if (*mode) {
      float* op = (float*)outv + (size_t)i * 64 + l8 * 8;
      *(float4*)op = make_float4(o[0], o[1], o[2], o[3]);
      *(float4*)(op + 4) = make_float4(o[4], o[5], o[6], o[7]);
    } else {
      uint4 ov;
      ov.x = pk2(o[0], o[1]);
      ov.y = pk2(o[2], o[3]);
      ov.z = pk2(o[4], o[5]);
      ov.w = pk2(o[6], o[7]);
      *(uint4*)((u16*)outv + (size_t)i * 64 + l8 * 8) = ov;
    }
  }
}

// ================= launch =================

extern "C" void kernel_launch(void* const* d_in, const int* in_sizes, int n_in,
                              void* d_out, int out_size, void* d_ws, size_t ws_size,
                              hipStream_t stream) {
  const void* x_raw  = d_in[0];
  const int*  ei     = (const int*)d_in[1];
  const void* W1_raw = d_in[2];
  const void* b1_raw = d_in[3];
  const void* W2_raw = d_in[4];
  const void* b2_raw = d_in[5];

  const int N = in_sizes[0] / 128;
  const int E = in_sizes[1] / 2;
  const int NP = ((N + 255) / 256) * 256;
  const int NB = NP / 256;
  const int NBK = (NP + (1 << BSH) - 1) >> BSH;   // buckets (<=64 for N<=128k)
  const int NBG = (NBK + 7) >> 3;

  char* ws = (char*)d_ws;
  size_t off = 0;
  auto alloc = [&](size_t bytes) -> void* {
    void* p = ws + off;
    off = (off + bytes + 255) & ~(size_t)255;
    return p;
  };
  int*   mode    = (int*)alloc(4);
  int*   cnt     = (int*)alloc((size_t)NP * 4);
  float* dinv    = (float*)alloc((size_t)NP * 4);
  int*   offs    = (int*)alloc((size_t)NP * 4);
  int*   cursor  = (int*)alloc((size_t)NP * 4);
  int*   bsum    = (int*)alloc(1024 * 4);
  int*   bstart  = (int*)alloc(256 * 4);
  int*   bcursor = (int*)alloc(256 * 4);
  int4*  ninfo   = (int4*)alloc((size_t)NP * 16);
  int2*  sp      = (int2*)alloc((size_t)E * 8);
  int2*  tmp     = (int2*)alloc((size_t)E * 8);
  u16*   W1b     = (u16*)alloc((size_t)128 * 128 * 2);
  u16*   b1b     = (u16*)alloc(128 * 2);
  u16*   W2t     = (u16*)alloc((size_t)64 * 128 * 2);
  u16*   b2b     = (u16*)alloc(64 * 2);
  u16*   h       = (u16*)alloc((size_t)N * 128 * 2);
  u16*   g       = (u16*)alloc((size_t)N * 64 * 2);

  const int eb = (E + 255) / 256;
  const int pb = (E + SEG - 1) / SEG;

  hipMemsetAsync(cnt, 0, (size_t)NP * 4, stream);
  prepcount_k<<<NB + eb, 256, 0, stream>>>(W1_raw, b1_raw, W2_raw, b2_raw,
                                           W1b, b1b, W2t, b2b, mode,
                                           ei + E, cnt, E, NB);
  scan1<<<NB, 256, 0, stream>>>(cnt, offs, bsum, NP);
  scan23<<<NB, 256, 0, stream>>>(offs, bsum, cursor, cnt, dinv, ninfo,
                                 bstart, bcursor, NP);
  part_k<<<pb, 256, 0, stream>>>(ei, ei + E, bcursor, tmp, E, NBK);
  scatter_k<<<64 * NBG, 256, 0, stream>>>(tmp, bstart, cursor, dinv, sp, E, NBK);
  gemm1_k<<<512, 256, 0, stream>>>(x_raw, W1b, h, N, mode);
  fusedB_k<<<(N + 15) / 16, 256, 0, stream>>>(h, sp, ninfo, b1b, W2t, g, N);
  agg2_k<<<(N + 31) / 32, 256, 0, stream>>>(g, sp, ninfo, b2b, d_out, N, mode);
}

// Round 4
// 194.364 us; speedup vs baseline: 1.3673x; 1.2079x over previous
//
#include <hip/hip_runtime.h>

// StandGCN2: 2-layer GCN, N=100000, E=600000, 128->128(relu)->64, bf16 I/O.
// R12 (resubmit; R3 bench was GPUAcquisitionTimeout - no data): compress the
// CSR chain. R11 proved radix partition kills scatter amplification (234.8us,
// fill chain all <42us). Remaining fat: count_k's 600k random global atomics +
// two 100k-node scan dispatches. After part_k groups edges by 512-node bucket,
// per-node count/scan/scatter is bucket-LOCAL:
//   nbuild_k (1 block/bucket, 196 blocks): LDS count (512 ctrs) -> LDS scan ->
//   ninfo/dinv -> LDS-rank scatter into sp. Bucket->XCD pinned (b%8), sp
//   window ~12KB L2-resident.
// sp now stores src ONLY (int, 2.4MB); consumers gather dinv[s] (400KB,
// L2-resident) - removes the cross-bucket dinv dep that forced a separate
// scatter dispatch. Bucket bases: consumers redundantly scan bhist in LDS
// (trivial) - no bscan dispatch.
// Pipeline (6 kernels + 2KB memset): memset(bhist,boff) -> prep_hist ->
// part -> nbuild -> gemm1 -> fusedB -> agg2.

typedef unsigned short u16;
typedef unsigned int u32;
typedef __attribute__((ext_vector_type(8))) short bf16x8;
typedef __attribute__((ext_vector_type(4))) float f32x4;

#define BSH 9                  // bucket shift: 512 nodes/bucket
#define BMSK ((1 << BSH) - 1)
#define MAXBK 256              // max buckets supported (N <= 131072)
#define SEG 2560               // edges per part_k block (LDS-staged)
#define HISTB 128              // histogram blocks

__device__ __forceinline__ u16 f2b(float f) {
  u32 u = __float_as_uint(f);
  u32 r = (u + 0x7FFFu + ((u >> 16) & 1u)) >> 16;
  return (u16)r;
}
__device__ __forceinline__ u32 pk2(float a, float b) {
  return (u32)f2b(a) | ((u32)f2b(b) << 16);
}
__device__ __forceinline__ void dec8(uint4 v, float f[8]) {
  f[0] = __uint_as_float(v.x << 16);
  f[1] = __uint_as_float(v.x & 0xFFFF0000u);
  f[2] = __uint_as_float(v.y << 16);
  f[3] = __uint_as_float(v.y & 0xFFFF0000u);
  f[4] = __uint_as_float(v.z << 16);
  f[5] = __uint_as_float(v.z & 0xFFFF0000u);
  f[6] = __uint_as_float(v.w << 16);
  f[7] = __uint_as_float(v.w & 0xFFFF0000u);
}
__device__ __forceinline__ void fma8(uint4 v, float d, float acc[8]) {
  acc[0] = fmaf(__uint_as_float(v.x << 16), d, acc[0]);
  acc[1] = fmaf(__uint_as_float(v.x & 0xFFFF0000u), d, acc[1]);
  acc[2] = fmaf(__uint_as_float(v.y << 16), d, acc[2]);
  acc[3] = fmaf(__uint_as_float(v.y & 0xFFFF0000u), d, acc[3]);
  acc[4] = fmaf(__uint_as_float(v.z << 16), d, acc[4]);
  acc[5] = fmaf(__uint_as_float(v.z & 0xFFFF0000u), d, acc[5]);
  acc[6] = fmaf(__uint_as_float(v.w << 16), d, acc[6]);
  acc[7] = fmaf(__uint_as_float(v.w & 0xFFFF0000u), d, acc[7]);
}

// ---- prep_hist: [0,PREPB) prep (probe + weight convert);
//      [PREPB,PREPB+HISTB) bucket histogram (LDS, then <=NBK global adds/block) ----

__global__ __launch_bounds__(256) void prep_hist_k(const void* __restrict__ W1,
                                                   const void* __restrict__ b1,
                                                   const void* __restrict__ W2,
                                                   const void* __restrict__ b2,
                                                   u16* __restrict__ W1b, u16* __restrict__ ob1,
                                                   u16* __restrict__ W2t, u16* __restrict__ ob2,
                                                   int* __restrict__ mode,
                                                   const int* __restrict__ dst,
                                                   int* __restrict__ bhist,
                                                   int E, int PREPB) {
  const int tid = threadIdx.x;

  if ((int)blockIdx.x >= PREPB) {
    __shared__ int lh[MAXBK];
    const int hb = (int)blockIdx.x - PREPB;
    for (int j = tid; j < MAXBK; j += 256) lh[j] = 0;
    __syncthreads();
    const int chunk = (E + HISTB - 1) / HISTB;
    const int e0 = hb * chunk;
    const int e1 = min(E, e0 + chunk);
    for (int e = e0 + tid; e < e1; e += 256) atomicAdd(&lh[dst[e] >> BSH], 1);
    __syncthreads();
    for (int j = tid; j < MAXBK; j += 256) {
      int v = lh[j];
      if (v) atomicAdd(&bhist[j], v);
    }
    return;
  }

  // prep role: block-local dtype probe + weight convert
  __shared__ int cnt_s;
  if (tid == 0) cnt_s = 0;
  __syncthreads();
  int c = 0;
  for (int j = tid; j < 4096; j += 256) {
    u32 e = (((const u16*)W1)[j] >> 7) & 0xFFu;
    if (e >= 100u && e <= 130u) c++;
  }
  atomicAdd(&cnt_s, c);
  __syncthreads();
  const int m = (cnt_s < 3328) ? 1 : 0;  // 1 = fp32
  if (blockIdx.x == 0 && tid == 0) *mode = m;

  int i = blockIdx.x * 256 + tid;
  if (i < 24768) {
    int j = i;
    const void* src;
    u16* dstp;
    int sidx, didx;
    if (j < 16384) {
      src = W1; dstp = W1b; sidx = j; didx = j;
    } else if ((j -= 16384) < 128) {
      src = b1; dstp = ob1; sidx = j; didx = j;
    } else if ((j -= 128) < 8192) {
      int nn = j >> 7, k = j & 127;               // W2t[n][k] = W2[k][n]
      src = W2; dstp = W2t; sidx = k * 64 + nn; didx = j;
    } else {
      j -= 8192;
      src = b2; dstp = ob2; sidx = j; didx = j;
    }
    dstp[didx] = m ? f2b(((const float*)src)[sidx]) : ((const u16*)src)[sidx];
  }
}

// ---- part_k: radix partition edges by dst bucket into tmp (sequential runs).
// Bucket bases derived in-block from bhist (LDS scan); space bulk-reserved via
// boff (one atomic per block-bucket) -> tmp writes are contiguous runs.

__global__ __launch_bounds__(256) void part_k(const int* __restrict__ src,
                                              const int* __restrict__ dst,
                                              const int* __restrict__ bhist,
                                              int* __restrict__ boff,
                                              int2* __restrict__ tmp,
                                              int E, int NBK) {
  __shared__ int ls[SEG];
  __shared__ int ld_[SEG];
  __shared__ int lh[MAXBK];
  __shared__ int base_[MAXBK];
  __shared__ int bsl[MAXBK];
  const int tid = threadIdx.x;

  // exclusive scan of bhist -> bsl (256 threads, 256 entries)
  int ov = (tid < NBK) ? bhist[tid] : 0;
  bsl[tid] = ov;
  __syncthreads();
#pragma unroll
  for (int off = 1; off < 256; off <<= 1) {
    int add = (tid >= off) ? bsl[tid - off] : 0;
    __syncthreads();
    bsl[tid] += add;
    __syncthreads();
  }
  bsl[tid] -= ov;  // exclusive
  if (tid < MAXBK) lh[tid] = 0;
  __syncthreads();

  const int e0 = blockIdx.x * SEG;
  const int len = min(SEG, E - e0);
  for (int j = tid; j < len; j += 256) {
    int s = src[e0 + j];
    int d = dst[e0 + j];
    ls[j] = s;
    ld_[j] = d;
    atomicAdd(&lh[d >> BSH], 1);
  }
  __syncthreads();
  if (tid < NBK) {
    int hh = lh[tid];
    base_[tid] = hh ? bsl[tid] + atomicAdd(&boff[tid], hh) : 0;
    lh[tid] = 0;  // reuse as rank counter
  }
  __syncthreads();
  for (int j = tid; j < len; j += 256) {
    int d = ld_[j];
    int bk = d >> BSH;
    int r = atomicAdd(&lh[bk], 1);
    tmp[base_[bk] + r] = make_int2(ls[j], d);
  }
}

// ---- nbuild_k: one block per bucket. LDS count (512) -> LDS scan -> write
// ninfo/dinv -> LDS-rank scatter tmp -> sp (src only). Bucket window L2-local;
// blockIdx=bucket -> XCD b%8 (round-robin) keeps it in one L2.

__global__ __launch_bounds__(256) void nbuild_k(const int2* __restrict__ tmp,
                                                const int* __restrict__ bhist,
                                                float* __restrict__ dinv,
                                                int4* __restrict__ ninfo,
                                                int* __restrict__ spI,
                                                int np, int NBK) {
  __shared__ int bsl[MAXBK];
  __shared__ int cntl[1 << BSH];
  __shared__ int curl[1 << BSH];
  __shared__ int sc2[256];
  const int tid = threadIdx.x;
  const int b = blockIdx.x;

  // exclusive scan of bhist -> bsl
  int ov = (tid < NBK) ? bhist[tid] : 0;
  bsl[tid] = ov;
  __syncthreads();
#pragma unroll
  for (int off = 1; off < 256; off <<= 1) {
    int add = (tid >= off) ? bsl[tid - off] : 0;
    __syncthreads();
    bsl[tid] += add;
    __syncthreads();
  }
  bsl[tid] -= ov;
  cntl[tid] = 0;
  cntl[tid + 256] = 0;
  curl[tid] = 0;
  curl[tid + 256] = 0;
  __syncthreads();

  const int bs = bsl[b];
  const int be = bs + bhist[b];
  const int lo = b << BSH;

  // pass 1: per-node count (LDS atomics)
  for (int e = bs + tid; e < be; e += 256) {
    int2 p = tmp[e];
    atomicAdd(&cntl[p.y & BMSK], 1);
  }
  __syncthreads();

  // scan 512 with 256 threads (2 elems/thread)
  const int c0 = cntl[2 * tid];
  const int c1 = cntl[2 * tid + 1];
  const int s2 = c0 + c1;
  sc2[tid] = s2;
  __syncthreads();
#pragma unroll
  for (int off = 1; off < 256; off <<= 1) {
    int add = (tid >= off) ? sc2[tid - off] : 0;
    __syncthreads();
    sc2[tid] += add;
    __syncthreads();
  }
  const int excl = sc2[tid] - s2;
  const int e0n = excl;
  const int e1n = excl + c0;

  // write node info + record offsets in cntl
  {
    int i0 = lo + 2 * tid;
    if (i0 < np) {
      float dv = rsqrtf((float)c0 + 1.0f);
      dinv[i0] = dv;
      ninfo[i0] = make_int4(bs + e0n, c0, __float_as_int(dv), 0);
    }
    int i1 = i0 + 1;
    if (i1 < np) {
      float dv = rsqrtf((float)c1 + 1.0f);
      dinv[i1] = dv;
      ninfo[i1] = make_int4(bs + e1n, c1, __float_as_int(dv), 0);
    }
  }
  cntl[2 * tid] = e0n;
  cntl[2 * tid + 1] = e1n;
  __syncthreads();

  // pass 2: scatter src into sp at node offsets (LDS rank)
  for (int e = bs + tid; e < be; e += 256) {
    int2 p = tmp[e];
    int loc = p.y & BMSK;
    int r = atomicAdd(&curl[loc], 1);
    spI[bs + cntl[loc] + r] = p.x;
  }
}

// ---------------- gemm1: h = x @ W1 (dense MFMA, R2-proven) ----------------

__global__ __launch_bounds__(256) void gemm1_k(const void* __restrict__ Araw,
                                               const u16* __restrict__ W,
                                               u16* __restrict__ out, int M,
                                               const int* __restrict__ mode) {
  __shared__ __align__(16) u16 Wt[128 * 136];
  __shared__ __align__(16) u16 As[64 * 136];
  const int tid = threadIdx.x;
  const int mcv = *mode;

  for (int idx = tid; idx < 128 * 128; idx += 256) {
    int n = idx & 127;
    int k = idx >> 7;
    Wt[n * 136 + k] = W[k * 128 + n];
  }
  __syncthreads();

  const int wv = tid >> 6, lane = tid & 63, lr = lane & 15, lq = lane >> 4;
  const int ntiles = (M + 63) >> 6;

  for (int t = blockIdx.x; t < ntiles; t += gridDim.x) {
    const int r0 = t * 64;
    __syncthreads();
    for (int idx = tid; idx < 64 * 16; idx += 256) {
      int row = idx >> 4, c = idx & 15;
      uint4 v = make_uint4(0u, 0u, 0u, 0u);
      if (r0 + row < M) {
        if (mcv) {
          const float* xf = (const float*)Araw + (size_t)(r0 + row) * 128 + c * 8;
          float4 f0 = *(const float4*)xf;
          float4 f1 = *(const float4*)(xf + 4);
          v.x = pk2(f0.x, f0.y);
          v.y = pk2(f0.z, f0.w);
          v.z = pk2(f1.x, f1.y);
          v.w = pk2(f1.z, f1.w);
        } else {
          v = *(const uint4*)((const u16*)Araw + (size_t)(r0 + row) * 128 + c * 8);
        }
      }
      *(uint4*)&As[row * 136 + c * 8] = v;
    }
    __syncthreads();

    bf16x8 a[4];
#pragma unroll
    for (int s = 0; s < 4; ++s)
      a[s] = *(const bf16x8*)&As[(wv * 16 + lr) * 136 + s * 32 + lq * 8];

#pragma unroll
    for (int nt = 0; nt < 8; ++nt) {
      f32x4 acc = {0.f, 0.f, 0.f, 0.f};
#pragma unroll
      for (int s = 0; s < 4; ++s) {
        bf16x8 b = *(const bf16x8*)&Wt[(nt * 16 + lr) * 136 + s * 32 + lq * 8];
        acc = __builtin_amdgcn_mfma_f32_16x16x32_bf16(a[s], b, acc, 0, 0, 0);
      }
#pragma unroll
      for (int r = 0; r < 4; ++r) {
        int row = r0 + wv * 16 + lq * 4 + r;
        if (row < M) out[(size_t)row * 128 + nt * 16 + lr] = f2b(acc[r]);
      }
    }
  }
}

// ---- fusedB: gather-aggregate h (16 nodes/block, quarter-wave, unroll-4)
//      -> +b1, relu -> LDS tile -> MFMA W2t -> g[N,64] ----
// sp carries src only; dinv[s] gathered (400KB, L2-resident).

__global__ __launch_bounds__(256) void fusedB_k(const u16* __restrict__ h,
                                                const int* __restrict__ spI,
                                                const int4* __restrict__ ninfo,
                                                const float* __restrict__ dinv,
                                                const u16* __restrict__ b1,
                                                const u16* __restrict__ W2t,
                                                u16* __restrict__ g, int n) {
  __shared__ __align__(16) u16 As[16 * 136];
  const int tid = threadIdx.x, wv = tid >> 6, lane = tid & 63;
  const int lq = lane >> 4, lr = lane & 15;
  const int base = blockIdx.x * 16;
  const int i = base + wv * 4 + lq;
  const bool valid = (i < n);

  int start = 0, c = 0;
  float di = 0.f;
  if (valid) {
    int4 ni = ninfo[i];
    start = ni.x;
    c = ni.y;
    di = __int_as_float(ni.z);
  }
  float acc[8];
  {
    uint4 v = valid ? *(const uint4*)(h + (size_t)i * 128 + lr * 8)
                    : make_uint4(0u, 0u, 0u, 0u);
    float f[8];
    dec8(v, f);
#pragma unroll
    for (int j = 0; j < 8; ++j) acc[j] = f[j] * di;
  }
  const int bl = lq * 16;
  for (int bs = 0; __any(bs < c); bs += 16) {
    int m = c - bs;
    m = m < 0 ? 0 : (m > 16 ? 16 : m);
    int s = 0;
    float dv = 0.f;
    if (lr < m) {
      s = spI[start + bs + lr];
      dv = dinv[s];
    }
    int mmw = m;
    mmw = max(mmw, __shfl_xor(mmw, 16));
    mmw = max(mmw, __shfl_xor(mmw, 32));
    for (int e = 0; e < mmw; e += 4) {
      int s0 = __shfl(s, bl + e), s1 = __shfl(s, bl + e + 1);
      int s2 = __shfl(s, bl + e + 2), s3 = __shfl(s, bl + e + 3);
      float d0 = __shfl(dv, bl + e);
      float d1 = __shfl(dv, bl + e + 1);
      float d2 = __shfl(dv, bl + e + 2);
      float d3 = __shfl(dv, bl + e + 3);
      uint4 v0 = *(const uint4*)(h + (size_t)s0 * 128 + lr * 8);
      uint4 v1 = *(const uint4*)(h + (size_t)s1 * 128 + lr * 8);
      uint4 v2 = *(const uint4*)(h + (size_t)s2 * 128 + lr * 8);
      uint4 v3 = *(const uint4*)(h + (size_t)s3 * 128 + lr * 8);
      fma8(v0, d0, acc);
      fma8(v1, d1, acc);
      fma8(v2, d2, acc);
      fma8(v3, d3, acc);
    }
  }
  {
    uint4 bv = *(const uint4*)(b1 + lr * 8);
    float bf[8];
    dec8(bv, bf);
    float o[8];
#pragma unroll
    for (int j = 0; j < 8; ++j) o[j] = fmaxf(fmaf(acc[j], di, bf[j]), 0.f);
    uint4 ov;
    ov.x = pk2(o[0], o[1]);
    ov.y = pk2(o[2], o[3]);
    ov.z = pk2(o[4], o[5]);
    ov.w = pk2(o[6], o[7]);
    *(uint4*)&As[(wv * 4 + lq) * 136 + lr * 8] = ov;
  }
  __syncthreads();

  bf16x8 a[4];
#pragma unroll
  for (int s = 0; s < 4; ++s)
    a[s] = *(const bf16x8*)&As[lr * 136 + s * 32 + lq * 8];
  {
    const int nt = wv;
    f32x4 acc4 = {0.f, 0.f, 0.f, 0.f};
#pragma unroll
    for (int s = 0; s < 4; ++s) {
      bf16x8 b = *(const bf16x8*)&W2t[(nt * 16 + lr) * 128 + s * 32 + lq * 8];
      acc4 = __builtin_amdgcn_mfma_f32_16x16x32_bf16(a[s], b, acc4, 0, 0, 0);
    }
#pragma unroll
    for (int r = 0; r < 4; ++r) {
      int row = base + lq * 4 + r;
      if (row < n) g[(size_t)row * 64 + nt * 16 + lr] = f2b(acc4[r]);
    }
  }
}

// ---- agg2: oct-wave over g, 8 nodes/wave, unroll-4 ----

__global__ __launch_bounds__(256) void agg2_k(const u16* __restrict__ g,
                                              const int* __restrict__ spI,
                                              const int4* __restrict__ ninfo,
                                              const float* __restrict__ dinv,
                                              const u16* __restrict__ b2,
                                              void* __restrict__ outv, int n,
                                              const int* __restrict__ mode) {
  const int lane = threadIdx.x & 63;
  const int o8 = lane >> 3, l8 = lane & 7;
  const int i = blockIdx.x * 32 + (threadIdx.x >> 6) * 8 + o8;
  const bool valid = (i < n);

  int start = 0, c = 0;
  float di = 0.f;
  if (valid) {
    int4 ni = ninfo[i];
    start = ni.x;
    c = ni.y;
    di = __int_as_float(ni.z);
  }
  float acc[8];
  {
    uint4 v = valid ? *(const uint4*)(g + (size_t)i * 64 + l8 * 8)
                    : make_uint4(0u, 0u, 0u, 0u);
    float f[8];
    dec8(v, f);
#pragma unroll
    for (int j = 0; j < 8; ++j) acc[j] = f[j] * di;
  }
  const int bl = o8 * 8;
  for (int base = 0; __any(base < c); base += 8) {
    int m = c - base;
    m = m < 0 ? 0 : (m > 8 ? 8 : m);
    int s = 0;
    float dv = 0.f;
    if (l8 < m) {
      s = spI[start + base + l8];
      dv = dinv[s];
    }
    int mmw = m;
    mmw = max(mmw, __shfl_xor(mmw, 8));
    mmw = max(mmw, __shfl_xor(mmw, 16));
    mmw = max(mmw, __shfl_xor(mmw, 32));
    for (int e = 0; e < mmw; e += 4) {
      int s0 = __shfl(s, bl + e), s1 = __shfl(s, bl + e + 1);
      int s2 = __shfl(s, bl + e + 2), s3 = __shfl(s, bl + e + 3);
      float d0 = __shfl(dv, bl + e);
      float d1 = __shfl(dv, bl + e + 1);
      float d2 = __shfl(dv, bl + e + 2);
      float d3 = __shfl(dv, bl + e + 3);
      uint4 v0 = *(const uint4*)(g + (size_t)s0 * 64 + l8 * 8);
      uint4 v1 = *(const uint4*)(g + (size_t)s1 * 64 + l8 * 8);
      uint4 v2 = *(const uint4*)(g + (size_t)s2 * 64 + l8 * 8);
      uint4 v3 = *(const uint4*)(g + (size_t)s3 * 64 + l8 * 8);
      fma8(v0, d0, acc);
      fma8(v1, d1, acc);
      fma8(v2, d2, acc);
      fma8(v3, d3, acc);
    }
  }
  if (valid) {
    uint4 bv = *(const uint4*)(b2 + l8 * 8);
    float bf[8];
    dec8(bv, bf);
    float o[8];
#pragma unroll
    for (int j = 0; j < 8; ++j) o[j] = fmaf(acc[j], di, bf[j]);
    if (*mode) {
      float* op = (float*)outv + (size_t)i * 64 + l8 * 8;
      *(float4*)op = make_float4(o[0], o[1], o[2], o[3]);
      *(float4*)(op + 4) = make_float4(o[4], o[5], o[6], o[7]);
    } else {
      uint4 ov;
      ov.x = pk2(o[0], o[1]);
      ov.y = pk2(o[2], o[3]);
      ov.z = pk2(o[4], o[5]);
      ov.w = pk2(o[6], o[7]);
      *(uint4*)((u16*)outv + (size_t)i * 64 + l8 * 8) = ov;
    }
  }
}

// ================= launch =================

extern "C" void kernel_launch(void* const* d_in, const int* in_sizes, int n_in,
                              void* d_out, int out_size, void* d_ws, size_t ws_size,
                              hipStream_t stream) {
  const void* x_raw  = d_in[0];
  const int*  ei     = (const int*)d_in[1];
  const void* W1_raw = d_in[2];
  const void* b1_raw = d_in[3];
  const void* W2_raw = d_in[4];
  const void* b2_raw = d_in[5];

  const int N = in_sizes[0] / 128;
  const int E = in_sizes[1] / 2;
  const int NP = ((N + 255) / 256) * 256;
  const int NBK = (NP + (1 << BSH) - 1) >> BSH;   // buckets (<=256 for N<=131072)
  const int PREPB = (24768 + 255) / 256;          // 97 prep blocks

  char* ws = (char*)d_ws;
  size_t off = 0;
  auto alloc = [&](size_t bytes) -> void* {
    void* p = ws + off;
    off = (off + bytes + 255) & ~(size_t)255;
    return p;
  };
  int*   mode    = (int*)alloc(4);
  int*   bz      = (int*)alloc((size_t)2 * MAXBK * 4);  // bhist | boff
  int*   bhist   = bz;
  int*   boff    = bz + MAXBK;
  float* dinv    = (float*)alloc((size_t)NP * 4);
  int4*  ninfo   = (int4*)alloc((size_t)NP * 16);
  int*   spI     = (int*)alloc((size_t)E * 4);
  int2*  tmp     = (int2*)alloc((size_t)E * 8);
  u16*   W1b     = (u16*)alloc((size_t)128 * 128 * 2);
  u16*   b1b     = (u16*)alloc(128 * 2);
  u16*   W2t     = (u16*)alloc((size_t)64 * 128 * 2);
  u16*   b2b     = (u16*)alloc(64 * 2);
  u16*   h       = (u16*)alloc((size_t)N * 128 * 2);
  u16*   g       = (u16*)alloc((size_t)N * 64 * 2);

  const int pb = (E + SEG - 1) / SEG;

  hipMemsetAsync(bz, 0, (size_t)2 * MAXBK * 4, stream);
  prep_hist_k<<<PREPB + HISTB, 256, 0, stream>>>(W1_raw, b1_raw, W2_raw, b2_raw,
                                                 W1b, b1b, W2t, b2b, mode,
                                                 ei + E, bhist, E, PREPB);
  part_k<<<pb, 256, 0, stream>>>(ei, ei + E, bhist, boff, tmp, E, NBK);
  nbuild_k<<<NBK, 256, 0, stream>>>(tmp, bhist, dinv, ninfo, spI, NP, NBK);
  gemm1_k<<<512, 256, 0, stream>>>(x_raw, W1b, h, N, mode);
  fusedB_k<<<(N + 15) / 16, 256, 0, stream>>>(h, spI, ninfo, dinv, b1b, W2t, g, N);
  agg2_k<<<(N + 31) / 32, 256, 0, stream>>>(g, spI, ninfo, dinv, b2b, d_out, N, mode);
}